// Round 1
// baseline (620.801 us; speedup 1.0000x reference)
//
#include <hip/hip_runtime.h>
#include <hip/hip_bf16.h>
#include <math.h>

#define N_ATOMS  50000
#define N_MOTIFS 50000
#define N_INC    600000
#define N_GRAPHS 512
#define H        64
#define MOTIF_DIM 94
#define HOUT     128
#define BN_EPS   1e-5f
#define TM       16   // rows (atoms/motifs) per tile in the linear kernels

__device__ __forceinline__ float softplus_f(float x) {
    // logaddexp(x, 0) = max(x,0) + log1p(exp(-|x|))
    return fmaxf(x, 0.0f) + log1pf(expf(-fabsf(x)));
}
__device__ __forceinline__ float sigmoid_f(float x) {
    return 1.0f / (1.0f + expf(-x));
}

// x[i][j] = embed_table[atom_z[i]][j]
__global__ __launch_bounds__(256) void embed_kernel(const int* __restrict__ atom_z,
                                                    const float* __restrict__ table,
                                                    float* __restrict__ x) {
    int i = blockIdx.x * 4 + (threadIdx.x >> 6);
    if (i >= N_ATOMS) return;
    int j = threadIdx.x & 63;
    x[(size_t)i * H + j] = table[(size_t)atom_z[i] * H + j];
}

// a_f = x @ w_f[0:64,:], a_c = x @ w_c[0:64,:]   (no bias; bias folded into motif side)
__global__ __launch_bounds__(256) void atom_linear(const float* __restrict__ x,
                                                   const float* __restrict__ w_f,
                                                   const float* __restrict__ w_c,
                                                   float* __restrict__ a_f,
                                                   float* __restrict__ a_c) {
    __shared__ float z[TM][H];
    int m0 = blockIdx.x * TM;
    int tid = threadIdx.x;
    for (int idx = tid; idx < TM * H; idx += 256) {
        int m = idx >> 6, k = idx & 63;
        z[m][k] = x[(size_t)(m0 + m) * H + k];
    }
    __syncthreads();
    int j = tid & 127;        // 0..127 : output column (j<64 -> f, else c)
    int mset = tid >> 7;      // 0..1
    const float* w = (j < H) ? (w_f + j) : (w_c + (j - H));
    float acc[8];
#pragma unroll
    for (int i = 0; i < 8; i++) acc[i] = 0.0f;
    for (int k = 0; k < H; k++) {
        float wv = w[(size_t)k * H];
#pragma unroll
        for (int i = 0; i < 8; i++) acc[i] += z[mset * 8 + i][k] * wv;
    }
    float* dst = (j < H) ? a_f : a_c;
    int jj = j & 63;
#pragma unroll
    for (int i = 0; i < 8; i++) {
        int m = m0 + mset * 8 + i;
        dst[(size_t)m * H + jj] = acc[i];
    }
}

// per-incidence: hx_sum[hid] += x[src]; counts for motifs and atoms
__global__ __launch_bounds__(256) void hx_scatter(const int* __restrict__ he,
                                                  const float* __restrict__ x,
                                                  float* __restrict__ hx_sum,
                                                  unsigned* __restrict__ cnt_motif,
                                                  unsigned* __restrict__ cnt_atom) {
    int e = blockIdx.x * 4 + (threadIdx.x >> 6);
    if (e >= N_INC) return;
    int j = threadIdx.x & 63;
    int s = he[e];
    int h = he[N_INC + e];
    atomicAdd(&hx_sum[(size_t)h * H + j], x[(size_t)s * H + j]);
    if (j == 0) {
        atomicAdd(&cnt_motif[h], 1u);
        atomicAdd(&cnt_atom[s], 1u);
    }
}

// m_f = [hx | motif_attr] @ w_{f}[64:222,:] + b_f   (and same for c)
__global__ __launch_bounds__(256) void motif_linear(const float* __restrict__ hx_sum,
                                                    const unsigned* __restrict__ cnt_motif,
                                                    const float* __restrict__ motif_attr,
                                                    const float* __restrict__ w_f,
                                                    const float* __restrict__ b_f,
                                                    const float* __restrict__ w_c,
                                                    const float* __restrict__ b_c,
                                                    float* __restrict__ m_f,
                                                    float* __restrict__ m_c) {
    __shared__ float z[TM][160];   // 158 used, pad to 160
    int m0 = blockIdx.x * TM;
    int tid = threadIdx.x;
    for (int idx = tid; idx < TM * H; idx += 256) {
        int m = idx >> 6, k = idx & 63;
        float inv = 1.0f / fmaxf((float)cnt_motif[m0 + m], 1.0f);
        z[m][k] = hx_sum[(size_t)(m0 + m) * H + k] * inv;
    }
    for (int idx = tid; idx < TM * MOTIF_DIM; idx += 256) {
        int m = idx / MOTIF_DIM, k = idx % MOTIF_DIM;
        z[m][H + k] = motif_attr[(size_t)(m0 + m) * MOTIF_DIM + k];
    }
    __syncthreads();
    int j = tid & 127;
    int mset = tid >> 7;
    const float* w = (j < H) ? (w_f + (size_t)H * H + j) : (w_c + (size_t)H * H + (j - H));
    float bias = (j < H) ? b_f[j] : b_c[j - H];
    float acc[8];
#pragma unroll
    for (int i = 0; i < 8; i++) acc[i] = bias;
    for (int k = 0; k < H + MOTIF_DIM; k++) {
        float wv = w[(size_t)k * H];
#pragma unroll
        for (int i = 0; i < 8; i++) acc[i] += z[mset * 8 + i][k] * wv;
    }
    float* dst = (j < H) ? m_f : m_c;
    int jj = j & 63;
#pragma unroll
    for (int i = 0; i < 8; i++) {
        int m = m0 + mset * 8 + i;
        dst[(size_t)m * H + jj] = acc[i];
    }
}

// per-incidence: msg = sigmoid(a_f[src]+m_f[hid]) * softplus(a_c[src]+m_c[hid]); out_sum[src] += msg
__global__ __launch_bounds__(256) void msg_scatter(const int* __restrict__ he,
                                                   const float* __restrict__ a_f,
                                                   const float* __restrict__ a_c,
                                                   const float* __restrict__ m_f,
                                                   const float* __restrict__ m_c,
                                                   float* __restrict__ out_sum) {
    int e = blockIdx.x * 4 + (threadIdx.x >> 6);
    if (e >= N_INC) return;
    int j = threadIdx.x & 63;
    int s = he[e];
    int h = he[N_INC + e];
    float f = a_f[(size_t)s * H + j] + m_f[(size_t)h * H + j];
    float c = a_c[(size_t)s * H + j] + m_c[(size_t)h * H + j];
    float msg = sigmoid_f(f) * softplus_f(c);
    atomicAdd(&out_sum[(size_t)s * H + j], msg);
}

// column-wise sum and sumsq of out (= out_sum/cnt) over atoms
__global__ __launch_bounds__(256) void bn_stats(const float* __restrict__ out_sum,
                                                const unsigned* __restrict__ cnt_atom,
                                                float* __restrict__ bn_sum,
                                                float* __restrict__ bn_sq) {
    __shared__ float ssum[256];
    __shared__ float ssq[256];
    int j = threadIdx.x & 63;
    int row = threadIdx.x >> 6;
    float s = 0.0f, q = 0.0f;
    for (int i = blockIdx.x * 4 + row; i < N_ATOMS; i += gridDim.x * 4) {
        float v = out_sum[(size_t)i * H + j] / fmaxf((float)cnt_atom[i], 1.0f);
        s += v; q += v * v;
    }
    ssum[threadIdx.x] = s; ssq[threadIdx.x] = q;
    __syncthreads();
    if (threadIdx.x < 64) {
        float ts = ssum[j] + ssum[64 + j] + ssum[128 + j] + ssum[192 + j];
        float tq = ssq[j] + ssq[64 + j] + ssq[128 + j] + ssq[192 + j];
        atomicAdd(&bn_sum[j], ts);
        atomicAdd(&bn_sq[j], tq);
    }
}

// BN (training stats) + residual + relu, then scatter-add into per-graph pool
__global__ __launch_bounds__(256) void bn_apply_pool(const float* __restrict__ out_sum,
                                                     const unsigned* __restrict__ cnt_atom,
                                                     const float* __restrict__ bn_sum,
                                                     const float* __restrict__ bn_sq,
                                                     const float* __restrict__ gamma,
                                                     const float* __restrict__ beta,
                                                     const float* __restrict__ x,
                                                     const int* __restrict__ batch,
                                                     float* __restrict__ g_sum,
                                                     unsigned* __restrict__ g_cnt) {
    int i = blockIdx.x * 4 + (threadIdx.x >> 6);
    if (i >= N_ATOMS) return;
    int j = threadIdx.x & 63;
    const float invN = 1.0f / (float)N_ATOMS;
    float mu = bn_sum[j] * invN;
    float var = bn_sq[j] * invN - mu * mu;
    float rstd = 1.0f / sqrtf(var + BN_EPS);
    float d = out_sum[(size_t)i * H + j] / fmaxf((float)cnt_atom[i], 1.0f);
    float o = (d - mu) * rstd * gamma[j] + beta[j];
    float xr = fmaxf(o + x[(size_t)i * H + j], 0.0f);
    int b = batch[i];
    atomicAdd(&g_sum[(size_t)b * H + j], xr);
    if (j == 0) atomicAdd(&g_cnt[b], 1u);
}

// per-graph: gv = g_sum/cnt; h = softplus(gv@w_l1+b_l1); out = h@w_out + b_out
__global__ __launch_bounds__(128) void head_kernel(const float* __restrict__ g_sum,
                                                   const unsigned* __restrict__ g_cnt,
                                                   const float* __restrict__ w_l1,
                                                   const float* __restrict__ b_l1,
                                                   const float* __restrict__ w_out,
                                                   const float* __restrict__ b_out,
                                                   float* __restrict__ out) {
    __shared__ float gv[H];
    __shared__ float red[HOUT];
    int g = blockIdx.x, t = threadIdx.x;
    if (t < H) gv[t] = g_sum[(size_t)g * H + t] / fmaxf((float)g_cnt[g], 1.0f);
    __syncthreads();
    float acc = b_l1[t];
    for (int k = 0; k < H; k++) acc += gv[k] * w_l1[(size_t)k * HOUT + t];
    float h = softplus_f(acc);
    red[t] = h * w_out[t];
    __syncthreads();
    for (int s = 64; s > 0; s >>= 1) {
        if (t < s) red[t] += red[t + s];
        __syncthreads();
    }
    if (t == 0) out[g] = red[0] + b_out[0];
}

extern "C" void kernel_launch(void* const* d_in, const int* in_sizes, int n_in,
                              void* d_out, int out_size, void* d_ws, size_t ws_size,
                              hipStream_t stream) {
    const int*   atom_z     = (const int*)  d_in[0];
    const float* motif_attr = (const float*)d_in[1];
    const int*   he         = (const int*)  d_in[2];
    const int*   batch      = (const int*)  d_in[3];
    const float* table      = (const float*)d_in[4];
    const float* w_f        = (const float*)d_in[5];
    const float* b_f        = (const float*)d_in[6];
    const float* w_c        = (const float*)d_in[7];
    const float* b_c        = (const float*)d_in[8];
    const float* gamma      = (const float*)d_in[9];
    const float* beta       = (const float*)d_in[10];
    const float* w_l1       = (const float*)d_in[11];
    const float* b_l1       = (const float*)d_in[12];
    const float* w_out      = (const float*)d_in[13];
    const float* b_out      = (const float*)d_in[14];
    float* out = (float*)d_out;

    // workspace layout (floats/uints, 4B each)
    float*    ws        = (float*)d_ws;
    float*    hx_sum    = ws;                               // 3,200,000
    float*    out_sum   = hx_sum + (size_t)N_MOTIFS * H;    // 3,200,000
    unsigned* cnt_motif = (unsigned*)(out_sum + (size_t)N_ATOMS * H); // 50,000
    unsigned* cnt_atom  = cnt_motif + N_MOTIFS;             // 50,000
    float*    bn_sum    = (float*)(cnt_atom + N_ATOMS);     // 64
    float*    bn_sq     = bn_sum + H;                       // 64
    float*    g_sum     = bn_sq + H;                        // 32,768
    unsigned* g_cnt     = (unsigned*)(g_sum + (size_t)N_GRAPHS * H); // 512
    char*     zero_end  = (char*)(g_cnt + N_GRAPHS);
    float*    x         = (float*)zero_end;                 // 3,200,000
    float*    a_f       = x   + (size_t)N_ATOMS * H;
    float*    a_c       = a_f + (size_t)N_ATOMS * H;
    float*    m_f       = a_c + (size_t)N_ATOMS * H;
    float*    m_c       = m_f + (size_t)N_MOTIFS * H;

    size_t zero_bytes = (size_t)(zero_end - (char*)d_ws);
    hipMemsetAsync(d_ws, 0, zero_bytes, stream);

    embed_kernel<<<N_ATOMS / 4, 256, 0, stream>>>(atom_z, table, x);
    atom_linear<<<N_ATOMS / TM, 256, 0, stream>>>(x, w_f, w_c, a_f, a_c);
    hx_scatter<<<N_INC / 4, 256, 0, stream>>>(he, x, hx_sum, cnt_motif, cnt_atom);
    motif_linear<<<N_MOTIFS / TM, 256, 0, stream>>>(hx_sum, cnt_motif, motif_attr,
                                                    w_f, b_f, w_c, b_c, m_f, m_c);
    msg_scatter<<<N_INC / 4, 256, 0, stream>>>(he, a_f, a_c, m_f, m_c, out_sum);
    bn_stats<<<1024, 256, 0, stream>>>(out_sum, cnt_atom, bn_sum, bn_sq);
    bn_apply_pool<<<N_ATOMS / 4, 256, 0, stream>>>(out_sum, cnt_atom, bn_sum, bn_sq,
                                                   gamma, beta, x, batch, g_sum, g_cnt);
    head_kernel<<<N_GRAPHS, 128, 0, stream>>>(g_sum, g_cnt, w_l1, b_l1, w_out, b_out, out);
}